// Round 2
// baseline (507.410 us; speedup 1.0000x reference)
//
#include <hip/hip_runtime.h>
#include <math.h>

// ---------------------------------------------------------------------------
// EncoderLayer: B=2,S=2048,D=768,H=12,DK=64,DFF=3072
// bf16 MFMA (16x16x32) for all matmuls, fp32 accumulate + fp32 pointwise.
// ---------------------------------------------------------------------------

using bf16   = __bf16;
using bf16x8 = __attribute__((ext_vector_type(8))) __bf16;
using bf16x4 = __attribute__((ext_vector_type(4))) __bf16;
using f32x4  = __attribute__((ext_vector_type(4))) float;

constexpr int S_   = 2048;
constexpr int D_   = 768;
constexpr int DFF_ = 3072;
constexpr int M_   = 4096;   // B*S
constexpr int BH_  = 24;     // B*H

__device__ __forceinline__ f32x4 mfma16(bf16x8 a, bf16x8 b, f32x4 c) {
    return __builtin_amdgcn_mfma_f32_16x16x32_bf16(a, b, c, 0, 0, 0);
}

// async global->LDS, 16B per lane; LDS dest must be wave-uniform base
__device__ __forceinline__ void gload16(const bf16* g, bf16* l) {
    __builtin_amdgcn_global_load_lds(
        (const __attribute__((address_space(1))) void*)g,
        (__attribute__((address_space(3))) void*)l, 16, 0, 0);
}

// ---------------------------------------------------------------------------
// pack x (fp32 -> bf16), 4 elems/thread
// ---------------------------------------------------------------------------
__global__ __launch_bounds__(256)
void pack_x_kernel(const float* __restrict__ x, bf16* __restrict__ xb) {
    const int i = blockIdx.x * 256 + threadIdx.x;
    float4 v = ((const float4*)x)[i];
    bf16x4 o;
    o[0] = (bf16)v.x; o[1] = (bf16)v.y; o[2] = (bf16)v.z; o[3] = (bf16)v.w;
    ((bf16x4*)xb)[i] = o;
}

// ---------------------------------------------------------------------------
// weight transpose+convert: in [K][N] fp32 -> out [N][K] bf16. 64x64 tiles.
// ---------------------------------------------------------------------------
__global__ __launch_bounds__(256)
void wt_kernel(const float* __restrict__ in, bf16* __restrict__ out, int K, int N) {
    __shared__ __align__(16) bf16 T[64][72];
    const int n0 = blockIdx.x * 64, k0 = blockIdx.y * 64;
    const int t  = threadIdx.x;
    const int r  = t >> 2, c0 = (t & 3) * 16;
    const float* src = in + (size_t)(k0 + r) * N + n0 + c0;
#pragma unroll
    for (int j = 0; j < 16; j += 4) {
        float4 v = *(const float4*)(src + j);
        T[r][c0 + j + 0] = (bf16)v.x;
        T[r][c0 + j + 1] = (bf16)v.y;
        T[r][c0 + j + 2] = (bf16)v.z;
        T[r][c0 + j + 3] = (bf16)v.w;
    }
    __syncthreads();
    bf16x8 o0, o1;
#pragma unroll
    for (int j = 0; j < 8; j++) { o0[j] = T[c0 + j][r]; o1[j] = T[c0 + 8 + j][r]; }
    bf16* dst = out + (size_t)(n0 + r) * K + k0 + c0;
    *(bf16x8*)(dst)     = o0;
    *(bf16x8*)(dst + 8) = o1;
}

// ---------------------------------------------------------------------------
// m97-structure GEMM: C = A[M,K] @ Bt[N,K]^T, 128x128 tile, BK=64,
// global_load_lds staging (width 16), 4 waves 2x2, 4x4 16x16 frags each.
// EPI: 0=QKV scatter(+bias, V written transposed), 1=Wo(+bias+resid fp32),
//      2=FFN1 gelu->bf16, 3=FFN2(+bias+resid fp32)
// ---------------------------------------------------------------------------
template<int EPI, int K>
__global__ __launch_bounds__(256)
void gemm_bt(const bf16* __restrict__ A, const bf16* __restrict__ Bt,
             const float* __restrict__ bias0, const float* __restrict__ bias1,
             const float* __restrict__ bias2, const float* __restrict__ resid,
             float* __restrict__ outf, bf16* __restrict__ outb,
             bf16* __restrict__ qo, bf16* __restrict__ ko, bf16* __restrict__ vo) {
    __shared__ __align__(16) bf16 Alds[128 * 64];
    __shared__ __align__(16) bf16 Blds[128 * 64];
    const int tid  = threadIdx.x;
    const int lane = tid & 63, w = tid >> 6;
    const int wm = w >> 1, wn = w & 1;
    const int m0 = blockIdx.y * 128, n0 = blockIdx.x * 128;
    const int g = lane >> 4, q = lane & 15;

    f32x4 acc[4][4] = {};

    const bf16* ga = A  + (long)(m0 + w * 32 + (lane >> 3)) * K + (lane & 7) * 8;
    const bf16* gb = Bt + (long)(n0 + w * 32 + (lane >> 3)) * K + (lane & 7) * 8;
    bf16* la = &Alds[(w * 32) * 64];
    bf16* lb = &Blds[(w * 32) * 64];

    for (int kt = 0; kt < K; kt += 64) {
        __syncthreads();
#pragma unroll
        for (int i = 0; i < 4; i++) {
            gload16(ga + kt + (long)i * 8 * K, la + i * 8 * 64);
            gload16(gb + kt + (long)i * 8 * K, lb + i * 8 * 64);
        }
        __syncthreads();
#pragma unroll
        for (int c = 0; c < 2; c++) {
            bf16x8 af[4], bfr[4];
#pragma unroll
            for (int i = 0; i < 4; i++)
                af[i] = *(const bf16x8*)&Alds[(wm * 64 + i * 16 + q) * 64 + c * 32 + g * 8];
#pragma unroll
            for (int i = 0; i < 4; i++)
                bfr[i] = *(const bf16x8*)&Blds[(wn * 64 + i * 16 + q) * 64 + c * 32 + g * 8];
#pragma unroll
            for (int mi = 0; mi < 4; mi++)
#pragma unroll
                for (int ni = 0; ni < 4; ni++)
                    acc[mi][ni] = mfma16(af[mi], bfr[ni], acc[mi][ni]);
        }
    }

    // epilogue: C/D frag layout col = lane&15, row = (lane>>4)*4 + r
#pragma unroll
    for (int mi = 0; mi < 4; mi++) {
#pragma unroll
        for (int ni = 0; ni < 4; ni++) {
            const int col  = n0 + wn * 64 + ni * 16 + q;
            const int row0 = m0 + wm * 64 + mi * 16 + g * 4;
            if (EPI == 0) {
                const int which = (col >= 1536) ? 2 : (col >= 768 ? 1 : 0);
                const int dd    = col - which * 768;
                const float bias = (which == 0 ? bias0 : which == 1 ? bias1 : bias2)[dd];
                const int hh = dd >> 6, dk = dd & 63;
                const long bh = (long)(row0 >> 11) * 12 + hh;
                if (which == 2) {
                    // V written transposed: Vt[bh][dk][s], 4 consecutive s -> b64
                    bf16x4 pv;
#pragma unroll
                    for (int r = 0; r < 4; r++) pv[r] = (bf16)(acc[mi][ni][r] + bias);
                    *(bf16x4*)&vo[(bh * 64 + dk) * 2048 + (row0 & 2047)] = pv;
                } else {
                    bf16* dst = (which == 0) ? qo : ko;
#pragma unroll
                    for (int r = 0; r < 4; r++)
                        dst[(bh * 2048 + ((row0 + r) & 2047)) * 64 + dk] =
                            (bf16)(acc[mi][ni][r] + bias);
                }
            } else if (EPI == 1 || EPI == 3) {
                const float bias = bias0[col];
#pragma unroll
                for (int r = 0; r < 4; r++) {
                    const int row = row0 + r;
                    outf[(long)row * 768 + col] =
                        acc[mi][ni][r] + bias + resid[(long)row * 768 + col];
                }
            } else { // EPI == 2: exact GELU -> bf16
                const float bias = bias0[col];
#pragma unroll
                for (int r = 0; r < 4; r++) {
                    const float v  = acc[mi][ni][r] + bias;
                    const float gl = 0.5f * v * (1.0f + erff(v * 0.70710678118654752f));
                    outb[(long)(row0 + r) * 3072 + col] = (bf16)gl;
                }
            }
        }
    }
}

// ---------------------------------------------------------------------------
// per-(head,row) L2 normalize of Q and K in place. One wave per 64-elem row.
// ---------------------------------------------------------------------------
__global__ __launch_bounds__(256)
void norm_qk_kernel(bf16* __restrict__ Q, bf16* __restrict__ K) {
    const int wid  = blockIdx.x * 4 + (threadIdx.x >> 6);
    const int lane = threadIdx.x & 63;
    bf16* buf = (wid < BH_ * S_) ? Q : K;
    const int row = (wid < BH_ * S_) ? wid : wid - BH_ * S_;
    bf16* ptr = buf + (long)row * 64 + lane;
    float v  = (float)*ptr;
    float ss = v * v;
#pragma unroll
    for (int o = 32; o; o >>= 1) ss += __shfl_xor(ss, o);
    float n = sqrtf(ss);
    *ptr = (bf16)(v / fmaxf(n, 1e-12f));
}

// ---------------------------------------------------------------------------
// Attention (no softmax): O = (Qn Kn^T)^2 @ V  per (b,h).  Barrier-free.
// 4 waves x 16 q-rows per block; 64-key tiles; swapped QK^T (mfma(K,Q)) so
// each lane's 4 S-values are k-contiguous -> one ds_write_b64 per MFMA into a
// wave-private double-buffered P; PV runs one tile behind QK (software pipe).
// K frags prefetched 2 tiles ahead, V frags 1 phase ahead.
// ---------------------------------------------------------------------------
__global__ __launch_bounds__(256, 3)
void attn_kernel(const bf16* __restrict__ Qn, const bf16* __restrict__ Kn,
                 const bf16* __restrict__ Vt, bf16* __restrict__ AO) {
    const int bh  = blockIdx.y;
    const int tid = threadIdx.x, lane = tid & 63, w = tid >> 6;
    const int g = lane >> 4, q15 = lane & 15;
    const int qbase = blockIdx.x * 64 + w * 16;
    __shared__ __align__(16) bf16 Pl[4][2][16][72];   // wave-private, dbuf

    const bf16* Qp = Qn + (long)bh * S_ * 64;
    const bf16* Kp = Kn + (long)bh * S_ * 64;
    const bf16* Vp = Vt + (long)bh * 64 * S_;

    bf16x8 qf[2];
    qf[0] = *(const bf16x8*)&Qp[(long)(qbase + q15) * 64 + g * 8];
    qf[1] = *(const bf16x8*)&Qp[(long)(qbase + q15) * 64 + 32 + g * 8];

    f32x4 o[4] = {};
    bf16x8 kf[2][4][2], vf[4][2];

    auto loadK = [&](int kt, int slot) {
#pragma unroll
        for (int ni = 0; ni < 4; ni++)
#pragma unroll
            for (int c = 0; c < 2; c++)
                kf[slot][ni][c] =
                    *(const bf16x8*)&Kp[(long)(kt + ni * 16 + q15) * 64 + c * 32 + g * 8];
    };
    auto loadV = [&](int kt) {
#pragma unroll
        for (int ni = 0; ni < 4; ni++)
#pragma unroll
            for (int c = 0; c < 2; c++)
                vf[ni][c] =
                    *(const bf16x8*)&Vp[(long)(ni * 16 + q15) * S_ + kt + c * 32 + g * 8];
    };
    auto qk = [&](int slot, int buf) {
        f32x4 s[4];
#pragma unroll
        for (int ni = 0; ni < 4; ni++) {
            s[ni] = mfma16(kf[slot][ni][0], qf[0], f32x4{0.f, 0.f, 0.f, 0.f});
            s[ni] = mfma16(kf[slot][ni][1], qf[1], s[ni]);
        }
        // lane holds S[k = kt + ni*16 + g*4 + r][q = qbase + q15]
#pragma unroll
        for (int ni = 0; ni < 4; ni++) {
            bf16x4 p4;
#pragma unroll
            for (int r = 0; r < 4; r++) { float v = s[ni][r]; p4[r] = (bf16)(v * v); }
            *(bf16x4*)&Pl[w][buf][q15][ni * 16 + g * 4] = p4;
        }
    };
    auto pv = [&](int buf) {
        bf16x8 pf0 = *(const bf16x8*)&Pl[w][buf][q15][g * 8];
        bf16x8 pf1 = *(const bf16x8*)&Pl[w][buf][q15][32 + g * 8];
#pragma unroll
        for (int ni = 0; ni < 4; ni++) {
            o[ni] = mfma16(pf0, vf[ni][0], o[ni]);
            o[ni] = mfma16(pf1, vf[ni][1], o[ni]);
        }
    };

    loadK(0, 0);
    qk(0, 0);
    loadK(64, 1);
    for (int t = 0; t < 31; t++) {
        loadV(t * 64);                         // used by pv(t) below
        qk((t + 1) & 1, (t + 1) & 1);          // kf already in flight
        if (t < 30) loadK((t + 2) * 64, t & 1);
        pv(t & 1);
    }
    loadV(31 * 64);
    pv(1);

    const int b = bh / 12, h = bh % 12;
#pragma unroll
    for (int ni = 0; ni < 4; ni++)
#pragma unroll
        for (int r = 0; r < 4; r++) {
            const int s = qbase + g * 4 + r;
            AO[((long)b * S_ + s) * D_ + h * 64 + ni * 16 + q15] = (bf16)o[ni][r];
        }
}

// ---------------------------------------------------------------------------
// LayerNorm over D=768. One block per row, 256 threads (3 elems each).
// ---------------------------------------------------------------------------
template<bool WB>
__global__ __launch_bounds__(256)
void ln_kernel(const float* __restrict__ y, const float* __restrict__ gamma,
               const float* __restrict__ beta, float* __restrict__ xo,
               bf16* __restrict__ xob) {
    __shared__ float sa[4], sb[4];
    const int row = blockIdx.x, t = threadIdx.x;
    const float* yr = y + (long)row * 768;
    float v0 = yr[t], v1 = yr[t + 256], v2 = yr[t + 512];
    float s  = v0 + v1 + v2;
    float ss = v0 * v0 + v1 * v1 + v2 * v2;
#pragma unroll
    for (int o = 32; o; o >>= 1) { s += __shfl_xor(s, o); ss += __shfl_xor(ss, o); }
    if ((t & 63) == 0) { sa[t >> 6] = s; sb[t >> 6] = ss; }
    __syncthreads();
    s  = sa[0] + sa[1] + sa[2] + sa[3];
    ss = sb[0] + sb[1] + sb[2] + sb[3];
    const float mu   = s * (1.0f / 768.0f);
    const float var  = ss * (1.0f / 768.0f) - mu * mu;
    const float rstd = rsqrtf(var + 1e-5f);
    float* xr = xo + (long)row * 768;
#pragma unroll
    for (int i = 0; i < 3; i++) {
        const int c = t + i * 256;
        const float vv = (i == 0) ? v0 : (i == 1) ? v1 : v2;
        const float ov = (vv - mu) * rstd * gamma[c] + beta[c];
        xr[c] = ov;
        if (WB) xob[(long)row * 768 + c] = (bf16)ov;
    }
}

// ---------------------------------------------------------------------------
extern "C" void kernel_launch(void* const* d_in, const int* in_sizes, int n_in,
                              void* d_out, int out_size, void* d_ws, size_t ws_size,
                              hipStream_t stream) {
    const float* x     = (const float*)d_in[0];
    const float* Wq    = (const float*)d_in[1];
    const float* bq    = (const float*)d_in[2];
    const float* Wk    = (const float*)d_in[3];
    const float* bk    = (const float*)d_in[4];
    const float* Wv    = (const float*)d_in[5];
    const float* bv    = (const float*)d_in[6];
    const float* Wo    = (const float*)d_in[7];
    const float* bo    = (const float*)d_in[8];
    const float* W1    = (const float*)d_in[9];
    const float* b1    = (const float*)d_in[10];
    const float* W2    = (const float*)d_in[11];
    const float* b2    = (const float*)d_in[12];
    const float* gamma = (const float*)d_in[13];
    const float* beta  = (const float*)d_in[14];

    char* p = (char*)d_ws;
    auto alloc = [&](size_t bytes) -> void* {
        void* r = p;
        p += (bytes + 255) & ~(size_t)255;
        return r;
    };
    bf16*  Xb    = (bf16*)alloc((size_t)M_ * D_ * 2);
    bf16*  Wqkvt = (bf16*)alloc((size_t)2304 * 768 * 2);
    bf16*  Wot   = (bf16*)alloc((size_t)768 * 768 * 2);
    bf16*  W1t   = (bf16*)alloc((size_t)3072 * 768 * 2);
    bf16*  W2t   = (bf16*)alloc((size_t)768 * 3072 * 2);
    bf16*  Qh    = (bf16*)alloc((size_t)BH_ * S_ * 64 * 2);
    bf16*  Kh    = (bf16*)alloc((size_t)BH_ * S_ * 64 * 2);
    bf16*  Vt    = (bf16*)alloc((size_t)BH_ * S_ * 64 * 2);
    bf16*  AO    = (bf16*)alloc((size_t)M_ * D_ * 2);
    float* y1    = (float*)alloc((size_t)M_ * D_ * 4);
    float* x1    = (float*)alloc((size_t)M_ * D_ * 4);
    bf16*  x1b   = (bf16*)alloc((size_t)M_ * D_ * 2);
    bf16*  hbuf  = (bf16*)alloc((size_t)M_ * DFF_ * 2);
    float* y2    = y1;  // y1 dead after LN1

    // pack + transpose weights
    pack_x_kernel<<<(M_ * D_) / 1024, 256, 0, stream>>>(x, Xb);
    wt_kernel<<<dim3(12, 12), 256, 0, stream>>>(Wq, Wqkvt,              768, 768);
    wt_kernel<<<dim3(12, 12), 256, 0, stream>>>(Wk, Wqkvt + 768 * 768,  768, 768);
    wt_kernel<<<dim3(12, 12), 256, 0, stream>>>(Wv, Wqkvt + 1536 * 768, 768, 768);
    wt_kernel<<<dim3(12, 12), 256, 0, stream>>>(Wo, Wot, 768, 768);
    wt_kernel<<<dim3(48, 12), 256, 0, stream>>>(W1, W1t, 768, 3072);
    wt_kernel<<<dim3(12, 48), 256, 0, stream>>>(W2, W2t, 3072, 768);

    // QKV projection -> Qh/Kh [bh][s][dk], Vt [bh][dk][s]
    gemm_bt<0, 768><<<dim3(18, 32), 256, 0, stream>>>(
        Xb, Wqkvt, bq, bk, bv, nullptr, nullptr, nullptr, Qh, Kh, Vt);
    norm_qk_kernel<<<(2 * BH_ * S_) / 4, 256, 0, stream>>>(Qh, Kh);

    // attention
    attn_kernel<<<dim3(S_ / 64, BH_), 256, 0, stream>>>(Qh, Kh, Vt, AO);

    // out projection + residual, LN1
    gemm_bt<1, 768><<<dim3(6, 32), 256, 0, stream>>>(
        AO, Wot, bo, nullptr, nullptr, x, y1, nullptr, nullptr, nullptr, nullptr);
    ln_kernel<true><<<M_, 256, 0, stream>>>(y1, gamma, beta, x1, x1b);

    // FFN
    gemm_bt<2, 768><<<dim3(24, 32), 256, 0, stream>>>(
        x1b, W1t, b1, nullptr, nullptr, nullptr, nullptr, hbuf, nullptr, nullptr, nullptr);
    gemm_bt<3, 3072><<<dim3(6, 32), 256, 0, stream>>>(
        hbuf, W2t, b2, nullptr, nullptr, x1, y2, nullptr, nullptr, nullptr, nullptr);
    ln_kernel<false><<<M_, 256, 0, stream>>>(y2, gamma, beta, (float*)d_out, nullptr);
}

// Round 3
// 380.081 us; speedup vs baseline: 1.3350x; 1.3350x over previous
//
#include <hip/hip_runtime.h>
#include <math.h>

// ---------------------------------------------------------------------------
// EncoderLayer: B=2,S=2048,D=768,H=12,DK=64,DFF=3072
// bf16 MFMA (16x16x32) for all matmuls, fp32 accumulate + fp32 pointwise.
// ---------------------------------------------------------------------------

using bf16   = __bf16;
using bf16x8 = __attribute__((ext_vector_type(8))) __bf16;
using bf16x4 = __attribute__((ext_vector_type(4))) __bf16;
using f32x4  = __attribute__((ext_vector_type(4))) float;

constexpr int S_   = 2048;
constexpr int D_   = 768;
constexpr int DFF_ = 3072;
constexpr int M_   = 4096;   // B*S
constexpr int BH_  = 24;     // B*H

__device__ __forceinline__ f32x4 mfma16(bf16x8 a, bf16x8 b, f32x4 c) {
    return __builtin_amdgcn_mfma_f32_16x16x32_bf16(a, b, c, 0, 0, 0);
}

// async global->LDS, 16B per lane; LDS dest must be wave-uniform base
__device__ __forceinline__ void gload16(const bf16* g, bf16* l) {
    __builtin_amdgcn_global_load_lds(
        (const __attribute__((address_space(1))) void*)g,
        (__attribute__((address_space(3))) void*)l, 16, 0, 0);
}

// ---------------------------------------------------------------------------
// pack x (fp32 -> bf16), 4 elems/thread
// ---------------------------------------------------------------------------
__global__ __launch_bounds__(256)
void pack_x_kernel(const float* __restrict__ x, bf16* __restrict__ xb) {
    const int i = blockIdx.x * 256 + threadIdx.x;
    float4 v = ((const float4*)x)[i];
    bf16x4 o;
    o[0] = (bf16)v.x; o[1] = (bf16)v.y; o[2] = (bf16)v.z; o[3] = (bf16)v.w;
    ((bf16x4*)xb)[i] = o;
}

// ---------------------------------------------------------------------------
// weight transpose+convert: in [K][N] fp32 -> out [N][K] bf16. 64x64 tiles.
// ---------------------------------------------------------------------------
__global__ __launch_bounds__(256)
void wt_kernel(const float* __restrict__ in, bf16* __restrict__ out, int K, int N) {
    __shared__ __align__(16) bf16 T[64][72];
    const int n0 = blockIdx.x * 64, k0 = blockIdx.y * 64;
    const int t  = threadIdx.x;
    const int r  = t >> 2, c0 = (t & 3) * 16;
    const float* src = in + (size_t)(k0 + r) * N + n0 + c0;
#pragma unroll
    for (int j = 0; j < 16; j += 4) {
        float4 v = *(const float4*)(src + j);
        T[r][c0 + j + 0] = (bf16)v.x;
        T[r][c0 + j + 1] = (bf16)v.y;
        T[r][c0 + j + 2] = (bf16)v.z;
        T[r][c0 + j + 3] = (bf16)v.w;
    }
    __syncthreads();
    bf16x8 o0, o1;
#pragma unroll
    for (int j = 0; j < 8; j++) { o0[j] = T[c0 + j][r]; o1[j] = T[c0 + 8 + j][r]; }
    bf16* dst = out + (size_t)(n0 + r) * K + k0 + c0;
    *(bf16x8*)(dst)     = o0;
    *(bf16x8*)(dst + 8) = o1;
}

// ---------------------------------------------------------------------------
// m97-structure GEMM: C = A[M,K] @ Bt[N,K]^T, BMxBN tile, BK=64,
// global_load_lds staging (width 16), 4 waves in WRxWC grid.
// EPI: 0=QKV scatter(+bias, V written transposed), 1=Wo(+bias+resid fp32),
//      2=FFN1 gelu->bf16, 3=FFN2(+bias+resid fp32)
// ---------------------------------------------------------------------------
template<int EPI, int K, int BM, int BN, int WR, int WC>
__global__ __launch_bounds__(256)
void gemm_bt(const bf16* __restrict__ A, const bf16* __restrict__ Bt,
             const float* __restrict__ bias0, const float* __restrict__ bias1,
             const float* __restrict__ bias2, const float* __restrict__ resid,
             float* __restrict__ outf, bf16* __restrict__ outb,
             bf16* __restrict__ qo, bf16* __restrict__ ko, bf16* __restrict__ vo) {
    constexpr int MR = BM / WR / 16;   // 16x16 frag repeats per wave (M)
    constexpr int NR = BN / WC / 16;   // 16x16 frag repeats per wave (N)
    __shared__ __align__(16) bf16 Alds[BM * 64];
    __shared__ __align__(16) bf16 Blds[BN * 64];
    const int tid  = threadIdx.x;
    const int lane = tid & 63, w = tid >> 6;
    const int wr = w / WC, wc = w % WC;
    const int m0 = blockIdx.y * BM, n0 = blockIdx.x * BN;
    const int g = lane >> 4, q = lane & 15;

    f32x4 acc[MR][NR] = {};

    const bf16* ga = A  + (long)(m0 + w * (BM / 4) + (lane >> 3)) * K + (lane & 7) * 8;
    const bf16* gb = Bt + (long)(n0 + w * (BN / 4) + (lane >> 3)) * K + (lane & 7) * 8;
    bf16* la = &Alds[(w * (BM / 4)) * 64];
    bf16* lb = &Blds[(w * (BN / 4)) * 64];

    for (int kt = 0; kt < K; kt += 64) {
        __syncthreads();
#pragma unroll
        for (int i = 0; i < BM / 32; i++)
            gload16(ga + kt + (long)i * 8 * K, la + i * 8 * 64);
#pragma unroll
        for (int i = 0; i < BN / 32; i++)
            gload16(gb + kt + (long)i * 8 * K, lb + i * 8 * 64);
        __syncthreads();
#pragma unroll
        for (int c = 0; c < 2; c++) {
            bf16x8 af[MR], bfr[NR];
#pragma unroll
            for (int i = 0; i < MR; i++)
                af[i] = *(const bf16x8*)&Alds[(wr * (BM / WR) + i * 16 + q) * 64 + c * 32 + g * 8];
#pragma unroll
            for (int i = 0; i < NR; i++)
                bfr[i] = *(const bf16x8*)&Blds[(wc * (BN / WC) + i * 16 + q) * 64 + c * 32 + g * 8];
#pragma unroll
            for (int mi = 0; mi < MR; mi++)
#pragma unroll
                for (int ni = 0; ni < NR; ni++)
                    acc[mi][ni] = mfma16(af[mi], bfr[ni], acc[mi][ni]);
        }
    }

    // epilogue: C/D frag layout col = lane&15, row = (lane>>4)*4 + r
#pragma unroll
    for (int mi = 0; mi < MR; mi++) {
#pragma unroll
        for (int ni = 0; ni < NR; ni++) {
            const int col  = n0 + wc * (BN / WC) + ni * 16 + q;
            const int row0 = m0 + wr * (BM / WR) + mi * 16 + g * 4;
            if (EPI == 0) {
                const int which = (col >= 1536) ? 2 : (col >= 768 ? 1 : 0);
                const int dd    = col - which * 768;
                const float bias = (which == 0 ? bias0 : which == 1 ? bias1 : bias2)[dd];
                const int hh = dd >> 6, dk = dd & 63;
                const long bh = (long)(row0 >> 11) * 12 + hh;
                if (which == 2) {
                    // V written transposed: Vt[bh][dk][s], 4 consecutive s -> b64
                    bf16x4 pv;
#pragma unroll
                    for (int r = 0; r < 4; r++) pv[r] = (bf16)(acc[mi][ni][r] + bias);
                    *(bf16x4*)&vo[(bh * 64 + dk) * 2048 + (row0 & 2047)] = pv;
                } else {
                    bf16* dst = (which == 0) ? qo : ko;
#pragma unroll
                    for (int r = 0; r < 4; r++)
                        dst[(bh * 2048 + ((row0 + r) & 2047)) * 64 + dk] =
                            (bf16)(acc[mi][ni][r] + bias);
                }
            } else if (EPI == 1 || EPI == 3) {
                const float bias = bias0[col];
#pragma unroll
                for (int r = 0; r < 4; r++) {
                    const int row = row0 + r;
                    outf[(long)row * 768 + col] =
                        acc[mi][ni][r] + bias + resid[(long)row * 768 + col];
                }
            } else { // EPI == 2: exact GELU -> bf16
                const float bias = bias0[col];
#pragma unroll
                for (int r = 0; r < 4; r++) {
                    const float v  = acc[mi][ni][r] + bias;
                    const float gl = 0.5f * v * (1.0f + erff(v * 0.70710678118654752f));
                    outb[(long)(row0 + r) * 3072 + col] = (bf16)gl;
                }
            }
        }
    }
}

// ---------------------------------------------------------------------------
// per-(head,row) L2 normalize of Q and K in place. One wave per 64-elem row.
// ---------------------------------------------------------------------------
__global__ __launch_bounds__(256)
void norm_qk_kernel(bf16* __restrict__ Q, bf16* __restrict__ K) {
    const int wid  = blockIdx.x * 4 + (threadIdx.x >> 6);
    const int lane = threadIdx.x & 63;
    bf16* buf = (wid < BH_ * S_) ? Q : K;
    const int row = (wid < BH_ * S_) ? wid : wid - BH_ * S_;
    bf16* ptr = buf + (long)row * 64 + lane;
    float v  = (float)*ptr;
    float ss = v * v;
#pragma unroll
    for (int o = 32; o; o >>= 1) ss += __shfl_xor(ss, o);
    float n = sqrtf(ss);
    *ptr = (bf16)(v / fmaxf(n, 1e-12f));
}

// ---------------------------------------------------------------------------
// Attention (no softmax): O = (Qn Kn^T)^2 @ V  per (b,h).  Barrier-free.
// 4 waves x 16 q-rows per block; 64-key tiles; swapped QK^T (mfma(K,Q)) so
// each lane's 4 S-values are k-contiguous -> one ds_write_b64 per MFMA into a
// wave-private double-buffered P; PV runs one tile behind QK.
// ALL register-array indices compile-time (rule #20): named kfA/kfB buffers,
// main loop manually unrolled x2.
// ---------------------------------------------------------------------------
__global__ __launch_bounds__(256, 2)
void attn_kernel(const bf16* __restrict__ Qn, const bf16* __restrict__ Kn,
                 const bf16* __restrict__ Vt, bf16* __restrict__ AO) {
    const int bh  = blockIdx.y;
    const int tid = threadIdx.x, lane = tid & 63, w = tid >> 6;
    const int g = lane >> 4, q15 = lane & 15;
    const int qbase = blockIdx.x * 64 + w * 16;
    __shared__ __align__(16) bf16 Pl[4][2][16][72];   // wave-private, dbuf
    bf16 (*P0)[72] = Pl[w][0];
    bf16 (*P1)[72] = Pl[w][1];

    const bf16* Qp = Qn + (long)bh * S_ * 64;
    const bf16* Kp = Kn + (long)bh * S_ * 64;
    const bf16* Vp = Vt + (long)bh * 64 * S_;

    bf16x8 qf0 = *(const bf16x8*)&Qp[(long)(qbase + q15) * 64 + g * 8];
    bf16x8 qf1 = *(const bf16x8*)&Qp[(long)(qbase + q15) * 64 + 32 + g * 8];

    f32x4 o[4] = {};
    bf16x8 kfA[4][2], kfB[4][2], vf[4][2];

    auto loadK = [&](int kt, bf16x8 (&kf)[4][2]) {
#pragma unroll
        for (int ni = 0; ni < 4; ni++)
#pragma unroll
            for (int c = 0; c < 2; c++)
                kf[ni][c] =
                    *(const bf16x8*)&Kp[(long)(kt + ni * 16 + q15) * 64 + c * 32 + g * 8];
    };
    auto loadV = [&](int kt) {
#pragma unroll
        for (int ni = 0; ni < 4; ni++)
#pragma unroll
            for (int c = 0; c < 2; c++)
                vf[ni][c] =
                    *(const bf16x8*)&Vp[(long)(ni * 16 + q15) * S_ + kt + c * 32 + g * 8];
    };
    auto qk = [&](bf16x8 (&kf)[4][2], bf16 (*P)[72]) {
        f32x4 s[4];
#pragma unroll
        for (int ni = 0; ni < 4; ni++) {
            s[ni] = mfma16(kf[ni][0], qf0, f32x4{0.f, 0.f, 0.f, 0.f});
            s[ni] = mfma16(kf[ni][1], qf1, s[ni]);
        }
        // lane holds S[k = kt + ni*16 + g*4 + r][q = qbase + q15]
#pragma unroll
        for (int ni = 0; ni < 4; ni++) {
            bf16x4 p4;
#pragma unroll
            for (int r = 0; r < 4; r++) { float v = s[ni][r]; p4[r] = (bf16)(v * v); }
            *(bf16x4*)&P[q15][ni * 16 + g * 4] = p4;
        }
    };
    auto pv = [&](bf16 (*P)[72]) {
        bf16x8 pf0 = *(const bf16x8*)&P[q15][g * 8];
        bf16x8 pf1 = *(const bf16x8*)&P[q15][32 + g * 8];
#pragma unroll
        for (int ni = 0; ni < 4; ni++) {
            o[ni] = mfma16(pf0, vf[ni][0], o[ni]);
            o[ni] = mfma16(pf1, vf[ni][1], o[ni]);
        }
    };

    loadK(0, kfA);
    qk(kfA, P0);
    loadK(64, kfB);
    for (int t = 0; t < 30; t += 2) {
        loadV(t * 64);
        qk(kfB, P1);               // tile t+1
        loadK((t + 2) * 64, kfA);
        pv(P0);                    // tile t
        loadV((t + 1) * 64);
        qk(kfA, P0);               // tile t+2
        loadK((t + 3) * 64, kfB);
        pv(P1);                    // tile t+1
    }
    // exit invariant: P0 = tile 30, kfB = tile 31
    loadV(30 * 64);
    qk(kfB, P1);                   // tile 31
    pv(P0);                        // tile 30
    loadV(31 * 64);
    pv(P1);                        // tile 31

    const int b = bh / 12, h = bh % 12;
#pragma unroll
    for (int ni = 0; ni < 4; ni++)
#pragma unroll
        for (int r = 0; r < 4; r++) {
            const int s = qbase + g * 4 + r;
            AO[((long)b * S_ + s) * D_ + h * 64 + ni * 16 + q15] = (bf16)o[ni][r];
        }
}

// ---------------------------------------------------------------------------
// LayerNorm over D=768. One block per row, 256 threads (3 elems each).
// ---------------------------------------------------------------------------
template<bool WB>
__global__ __launch_bounds__(256)
void ln_kernel(const float* __restrict__ y, const float* __restrict__ gamma,
               const float* __restrict__ beta, float* __restrict__ xo,
               bf16* __restrict__ xob) {
    __shared__ float sa[4], sb[4];
    const int row = blockIdx.x, t = threadIdx.x;
    const float* yr = y + (long)row * 768;
    float v0 = yr[t], v1 = yr[t + 256], v2 = yr[t + 512];
    float s  = v0 + v1 + v2;
    float ss = v0 * v0 + v1 * v1 + v2 * v2;
#pragma unroll
    for (int o = 32; o; o >>= 1) { s += __shfl_xor(s, o); ss += __shfl_xor(ss, o); }
    if ((t & 63) == 0) { sa[t >> 6] = s; sb[t >> 6] = ss; }
    __syncthreads();
    s  = sa[0] + sa[1] + sa[2] + sa[3];
    ss = sb[0] + sb[1] + sb[2] + sb[3];
    const float mu   = s * (1.0f / 768.0f);
    const float var  = ss * (1.0f / 768.0f) - mu * mu;
    const float rstd = rsqrtf(var + 1e-5f);
    float* xr = xo + (long)row * 768;
#pragma unroll
    for (int i = 0; i < 3; i++) {
        const int c = t + i * 256;
        const float vv = (i == 0) ? v0 : (i == 1) ? v1 : v2;
        const float ov = (vv - mu) * rstd * gamma[c] + beta[c];
        xr[c] = ov;
        if (WB) xob[(long)row * 768 + c] = (bf16)ov;
    }
}

// ---------------------------------------------------------------------------
extern "C" void kernel_launch(void* const* d_in, const int* in_sizes, int n_in,
                              void* d_out, int out_size, void* d_ws, size_t ws_size,
                              hipStream_t stream) {
    const float* x     = (const float*)d_in[0];
    const float* Wq    = (const float*)d_in[1];
    const float* bq    = (const float*)d_in[2];
    const float* Wk    = (const float*)d_in[3];
    const float* bk    = (const float*)d_in[4];
    const float* Wv    = (const float*)d_in[5];
    const float* bv    = (const float*)d_in[6];
    const float* Wo    = (const float*)d_in[7];
    const float* bo    = (const float*)d_in[8];
    const float* W1    = (const float*)d_in[9];
    const float* b1    = (const float*)d_in[10];
    const float* W2    = (const float*)d_in[11];
    const float* b2    = (const float*)d_in[12];
    const float* gamma = (const float*)d_in[13];
    const float* beta  = (const float*)d_in[14];

    char* p = (char*)d_ws;
    auto alloc = [&](size_t bytes) -> void* {
        void* r = p;
        p += (bytes + 255) & ~(size_t)255;
        return r;
    };
    bf16*  Xb    = (bf16*)alloc((size_t)M_ * D_ * 2);
    bf16*  Wqkvt = (bf16*)alloc((size_t)2304 * 768 * 2);
    bf16*  Wot   = (bf16*)alloc((size_t)768 * 768 * 2);
    bf16*  W1t   = (bf16*)alloc((size_t)3072 * 768 * 2);
    bf16*  W2t   = (bf16*)alloc((size_t)768 * 3072 * 2);
    bf16*  Qh    = (bf16*)alloc((size_t)BH_ * S_ * 64 * 2);
    bf16*  Kh    = (bf16*)alloc((size_t)BH_ * S_ * 64 * 2);
    bf16*  Vt    = (bf16*)alloc((size_t)BH_ * S_ * 64 * 2);
    bf16*  AO    = (bf16*)alloc((size_t)M_ * D_ * 2);
    float* y1    = (float*)alloc((size_t)M_ * D_ * 4);
    float* x1    = (float*)alloc((size_t)M_ * D_ * 4);
    bf16*  x1b   = (bf16*)alloc((size_t)M_ * D_ * 2);
    bf16*  hbuf  = (bf16*)alloc((size_t)M_ * DFF_ * 2);
    float* y2    = y1;  // y1 dead after LN1

    // pack + transpose weights
    pack_x_kernel<<<(M_ * D_) / 1024, 256, 0, stream>>>(x, Xb);
    wt_kernel<<<dim3(12, 12), 256, 0, stream>>>(Wq, Wqkvt,              768, 768);
    wt_kernel<<<dim3(12, 12), 256, 0, stream>>>(Wk, Wqkvt + 768 * 768,  768, 768);
    wt_kernel<<<dim3(12, 12), 256, 0, stream>>>(Wv, Wqkvt + 1536 * 768, 768, 768);
    wt_kernel<<<dim3(12, 12), 256, 0, stream>>>(Wo, Wot, 768, 768);
    wt_kernel<<<dim3(48, 12), 256, 0, stream>>>(W1, W1t, 768, 3072);
    wt_kernel<<<dim3(12, 48), 256, 0, stream>>>(W2, W2t, 3072, 768);

    // QKV projection -> Qh/Kh [bh][s][dk], Vt [bh][dk][s]
    gemm_bt<0, 768, 128, 128, 2, 2><<<dim3(18, 32), 256, 0, stream>>>(
        Xb, Wqkvt, bq, bk, bv, nullptr, nullptr, nullptr, Qh, Kh, Vt);
    norm_qk_kernel<<<(2 * BH_ * S_) / 4, 256, 0, stream>>>(Qh, Kh);

    // attention
    attn_kernel<<<dim3(S_ / 64, BH_), 256, 0, stream>>>(Qh, Kh, Vt, AO);

    // out projection + residual, LN1  (64x128 tiles -> 384 blocks)
    gemm_bt<1, 768, 64, 128, 1, 4><<<dim3(6, 64), 256, 0, stream>>>(
        AO, Wot, bo, nullptr, nullptr, x, y1, nullptr, nullptr, nullptr, nullptr);
    ln_kernel<true><<<M_, 256, 0, stream>>>(y1, gamma, beta, x1, x1b);

    // FFN
    gemm_bt<2, 768, 128, 128, 2, 2><<<dim3(24, 32), 256, 0, stream>>>(
        x1b, W1t, b1, nullptr, nullptr, nullptr, nullptr, hbuf, nullptr, nullptr, nullptr);
    gemm_bt<3, 3072, 64, 128, 1, 4><<<dim3(6, 64), 256, 0, stream>>>(
        hbuf, W2t, b2, nullptr, nullptr, x1, y2, nullptr, nullptr, nullptr, nullptr);
    ln_kernel<false><<<M_, 256, 0, stream>>>(y2, gamma, beta, (float*)d_out, nullptr);
}

// Round 4
// 254.913 us; speedup vs baseline: 1.9905x; 1.4910x over previous
//
#include <hip/hip_runtime.h>
#include <math.h>

// ---------------------------------------------------------------------------
// EncoderLayer: B=2,S=2048,D=768,H=12,DK=64,DFF=3072
// bf16 MFMA (16x16x32) for all matmuls, fp32 accumulate + fp32 pointwise.
// ---------------------------------------------------------------------------

using bf16   = __bf16;
using bf16x8 = __attribute__((ext_vector_type(8))) __bf16;
using bf16x4 = __attribute__((ext_vector_type(4))) __bf16;
using f32x4  = __attribute__((ext_vector_type(4))) float;

constexpr int S_   = 2048;
constexpr int D_   = 768;
constexpr int DFF_ = 3072;
constexpr int M_   = 4096;   // B*S
constexpr int BH_  = 24;     // B*H

__device__ __forceinline__ f32x4 mfma16(bf16x8 a, bf16x8 b, f32x4 c) {
    return __builtin_amdgcn_mfma_f32_16x16x32_bf16(a, b, c, 0, 0, 0);
}

// async global->LDS, 16B per lane; LDS dest must be wave-uniform base
__device__ __forceinline__ void gload16(const bf16* g, bf16* l) {
    __builtin_amdgcn_global_load_lds(
        (const __attribute__((address_space(1))) void*)g,
        (__attribute__((address_space(3))) void*)l, 16, 0, 0);
}

// ---------------------------------------------------------------------------
// pack x (fp32 -> bf16), 4 elems/thread
// ---------------------------------------------------------------------------
__global__ __launch_bounds__(256)
void pack_x_kernel(const float* __restrict__ x, bf16* __restrict__ xb) {
    const int i = blockIdx.x * 256 + threadIdx.x;
    float4 v = ((const float4*)x)[i];
    bf16x4 o;
    o[0] = (bf16)v.x; o[1] = (bf16)v.y; o[2] = (bf16)v.z; o[3] = (bf16)v.w;
    ((bf16x4*)xb)[i] = o;
}

// ---------------------------------------------------------------------------
// weight transpose+convert: in [K][N] fp32 -> out [N][K] bf16. 64x64 tiles.
// ---------------------------------------------------------------------------
__global__ __launch_bounds__(256)
void wt_kernel(const float* __restrict__ in, bf16* __restrict__ out, int K, int N) {
    __shared__ __align__(16) bf16 T[64][72];
    const int n0 = blockIdx.x * 64, k0 = blockIdx.y * 64;
    const int t  = threadIdx.x;
    const int r  = t >> 2, c0 = (t & 3) * 16;
    const float* src = in + (size_t)(k0 + r) * N + n0 + c0;
#pragma unroll
    for (int j = 0; j < 16; j += 4) {
        float4 v = *(const float4*)(src + j);
        T[r][c0 + j + 0] = (bf16)v.x;
        T[r][c0 + j + 1] = (bf16)v.y;
        T[r][c0 + j + 2] = (bf16)v.z;
        T[r][c0 + j + 3] = (bf16)v.w;
    }
    __syncthreads();
    bf16x8 o0, o1;
#pragma unroll
    for (int j = 0; j < 8; j++) { o0[j] = T[c0 + j][r]; o1[j] = T[c0 + 8 + j][r]; }
    bf16* dst = out + (size_t)(n0 + r) * K + k0 + c0;
    *(bf16x8*)(dst)     = o0;
    *(bf16x8*)(dst + 8) = o1;
}

// ---------------------------------------------------------------------------
// m97-structure GEMM: C = A[M,K] @ Bt[N,K]^T, BMxBN tile, BK=64,
// global_load_lds staging (width 16), 4 waves in WRxWC grid.
// EPI: 0=QKV scatter(+bias, V written transposed), 1=Wo(+bias+resid fp32),
//      2=FFN1 gelu->bf16, 3=FFN2(+bias+resid fp32)
// ---------------------------------------------------------------------------
template<int EPI, int K, int BM, int BN, int WR, int WC>
__global__ __launch_bounds__(256)
void gemm_bt(const bf16* __restrict__ A, const bf16* __restrict__ Bt,
             const float* __restrict__ bias0, const float* __restrict__ bias1,
             const float* __restrict__ bias2, const float* __restrict__ resid,
             float* __restrict__ outf, bf16* __restrict__ outb,
             bf16* __restrict__ qo, bf16* __restrict__ ko, bf16* __restrict__ vo) {
    constexpr int MR = BM / WR / 16;   // 16x16 frag repeats per wave (M)
    constexpr int NR = BN / WC / 16;   // 16x16 frag repeats per wave (N)
    __shared__ __align__(16) bf16 Alds[BM * 64];
    __shared__ __align__(16) bf16 Blds[BN * 64];
    const int tid  = threadIdx.x;
    const int lane = tid & 63, w = tid >> 6;
    const int wr = w / WC, wc = w % WC;
    const int m0 = blockIdx.y * BM, n0 = blockIdx.x * BN;
    const int g = lane >> 4, q = lane & 15;

    f32x4 acc[MR][NR] = {};

    const bf16* ga = A  + (long)(m0 + w * (BM / 4) + (lane >> 3)) * K + (lane & 7) * 8;
    const bf16* gb = Bt + (long)(n0 + w * (BN / 4) + (lane >> 3)) * K + (lane & 7) * 8;
    bf16* la = &Alds[(w * (BM / 4)) * 64];
    bf16* lb = &Blds[(w * (BN / 4)) * 64];

    for (int kt = 0; kt < K; kt += 64) {
        __syncthreads();
#pragma unroll
        for (int i = 0; i < BM / 32; i++)
            gload16(ga + kt + (long)i * 8 * K, la + i * 8 * 64);
#pragma unroll
        for (int i = 0; i < BN / 32; i++)
            gload16(gb + kt + (long)i * 8 * K, lb + i * 8 * 64);
        __syncthreads();
#pragma unroll
        for (int c = 0; c < 2; c++) {
            bf16x8 af[MR], bfr[NR];
#pragma unroll
            for (int i = 0; i < MR; i++)
                af[i] = *(const bf16x8*)&Alds[(wr * (BM / WR) + i * 16 + q) * 64 + c * 32 + g * 8];
#pragma unroll
            for (int i = 0; i < NR; i++)
                bfr[i] = *(const bf16x8*)&Blds[(wc * (BN / WC) + i * 16 + q) * 64 + c * 32 + g * 8];
#pragma unroll
            for (int mi = 0; mi < MR; mi++)
#pragma unroll
                for (int ni = 0; ni < NR; ni++)
                    acc[mi][ni] = mfma16(af[mi], bfr[ni], acc[mi][ni]);
        }
    }

    // epilogue: C/D frag layout col = lane&15, row = (lane>>4)*4 + r
#pragma unroll
    for (int mi = 0; mi < MR; mi++) {
#pragma unroll
        for (int ni = 0; ni < NR; ni++) {
            const int col  = n0 + wc * (BN / WC) + ni * 16 + q;
            const int row0 = m0 + wr * (BM / WR) + mi * 16 + g * 4;
            if (EPI == 0) {
                const int which = (col >= 1536) ? 2 : (col >= 768 ? 1 : 0);
                const int dd    = col - which * 768;
                const float bias = (which == 0 ? bias0 : which == 1 ? bias1 : bias2)[dd];
                const int hh = dd >> 6, dk = dd & 63;
                const long bh = (long)(row0 >> 11) * 12 + hh;
                if (which == 2) {
                    // V written transposed: Vt[bh][dk][s], 4 consecutive s -> b64
                    bf16x4 pv;
#pragma unroll
                    for (int r = 0; r < 4; r++) pv[r] = (bf16)(acc[mi][ni][r] + bias);
                    *(bf16x4*)&vo[(bh * 64 + dk) * 2048 + (row0 & 2047)] = pv;
                } else {
                    bf16* dst = (which == 0) ? qo : ko;
#pragma unroll
                    for (int r = 0; r < 4; r++)
                        dst[(bh * 2048 + ((row0 + r) & 2047)) * 64 + dk] =
                            (bf16)(acc[mi][ni][r] + bias);
                }
            } else if (EPI == 1 || EPI == 3) {
                const float bias = bias0[col];
#pragma unroll
                for (int r = 0; r < 4; r++) {
                    const int row = row0 + r;
                    outf[(long)row * 768 + col] =
                        acc[mi][ni][r] + bias + resid[(long)row * 768 + col];
                }
            } else { // EPI == 2: exact GELU -> bf16
                const float bias = bias0[col];
#pragma unroll
                for (int r = 0; r < 4; r++) {
                    const float v  = acc[mi][ni][r] + bias;
                    const float gl = 0.5f * v * (1.0f + erff(v * 0.70710678118654752f));
                    outb[(long)(row0 + r) * 3072 + col] = (bf16)gl;
                }
            }
        }
    }
}

// ---------------------------------------------------------------------------
// per-(head,row) L2 normalize of Q and K in place. One wave per 64-elem row.
// ---------------------------------------------------------------------------
__global__ __launch_bounds__(256)
void norm_qk_kernel(bf16* __restrict__ Q, bf16* __restrict__ K) {
    const int wid  = blockIdx.x * 4 + (threadIdx.x >> 6);
    const int lane = threadIdx.x & 63;
    bf16* buf = (wid < BH_ * S_) ? Q : K;
    const int row = (wid < BH_ * S_) ? wid : wid - BH_ * S_;
    bf16* ptr = buf + (long)row * 64 + lane;
    float v  = (float)*ptr;
    float ss = v * v;
#pragma unroll
    for (int o = 32; o; o >>= 1) ss += __shfl_xor(ss, o);
    float n = sqrtf(ss);
    *ptr = (bf16)(v / fmaxf(n, 1e-12f));
}

// ---------------------------------------------------------------------------
// Attention (no softmax): O = (Qn Kn^T)^2 @ V  per (b,h).
// Block = 4 waves x 16 q-rows = 64 q-rows; 64-key tiles.
// K and Vt tiles staged COOPERATIVELY into double-buffered padded LDS
// ([64][72] -> all reads/writes <=2-way bank aliasing = free), coalesced
// b128 global loads, one __syncthreads per tile, two named register staging
// sets (A/B) with the loop unrolled x2 so the prefetch pipeline is
// structural (compile-time reg indices everywhere, rule #20).
// Swapped QK^T (mfma(K,Q)) -> P written k-contiguous (b64) into wave-private
// padded P, re-read as PV A-fragment. 16 MFMA per tile per wave.
// ---------------------------------------------------------------------------
__global__ __launch_bounds__(256, 2)
void attn_kernel(const bf16* __restrict__ Qn, const bf16* __restrict__ Kn,
                 const bf16* __restrict__ Vt, bf16* __restrict__ AO) {
    const int bh  = blockIdx.y;
    const int tid = threadIdx.x, lane = tid & 63, w = tid >> 6;
    const int g = lane >> 4, q15 = lane & 15;
    const int qbase = blockIdx.x * 64 + w * 16;

    __shared__ __align__(16) bf16 Kl[2][64][72];
    __shared__ __align__(16) bf16 Vl[2][64][72];
    __shared__ __align__(16) bf16 Pl[4][16][72];
    bf16 (*Pw)[72] = Pl[w];

    const bf16* Qp = Qn + (long)bh * S_ * 64;
    const bf16* Kp = Kn + (long)bh * S_ * 64;
    const bf16* Vp = Vt + (long)bh * 64 * S_;

    const int srow = tid >> 3, scol = (tid & 7) * 8;   // staging coords

    bf16x8 qf0 = *(const bf16x8*)&Qp[(long)(qbase + q15) * 64 + g * 8];
    bf16x8 qf1 = *(const bf16x8*)&Qp[(long)(qbase + q15) * 64 + 32 + g * 8];

    f32x4 o[4] = {};

    // ---- staging helpers (named reg sets, all-coalesced b128) ----
    bf16x8 aK0, aK1, aV0, aV1, bK0, bK1, bV0, bV1;
    auto gloadA = [&](int kt) {
        aK0 = *(const bf16x8*)&Kp[(long)(kt + srow) * 64 + scol];
        aK1 = *(const bf16x8*)&Kp[(long)(kt + 32 + srow) * 64 + scol];
        aV0 = *(const bf16x8*)&Vp[(long)srow * S_ + kt + scol];
        aV1 = *(const bf16x8*)&Vp[(long)(32 + srow) * S_ + kt + scol];
    };
    auto gloadB = [&](int kt) {
        bK0 = *(const bf16x8*)&Kp[(long)(kt + srow) * 64 + scol];
        bK1 = *(const bf16x8*)&Kp[(long)(kt + 32 + srow) * 64 + scol];
        bV0 = *(const bf16x8*)&Vp[(long)srow * S_ + kt + scol];
        bV1 = *(const bf16x8*)&Vp[(long)(32 + srow) * S_ + kt + scol];
    };
    auto stageA = [&](int buf) {
        *(bf16x8*)&Kl[buf][srow][scol]      = aK0;
        *(bf16x8*)&Kl[buf][32 + srow][scol] = aK1;
        *(bf16x8*)&Vl[buf][srow][scol]      = aV0;
        *(bf16x8*)&Vl[buf][32 + srow][scol] = aV1;
    };
    auto stageB = [&](int buf) {
        *(bf16x8*)&Kl[buf][srow][scol]      = bK0;
        *(bf16x8*)&Kl[buf][32 + srow][scol] = bK1;
        *(bf16x8*)&Vl[buf][srow][scol]      = bV0;
        *(bf16x8*)&Vl[buf][32 + srow][scol] = bV1;
    };

    // ---- compute one 64-key tile from LDS buffer `cur` ----
    auto compute = [&](int cur) {
        bf16x8 kf[4][2];
#pragma unroll
        for (int ni = 0; ni < 4; ni++)
#pragma unroll
            for (int c = 0; c < 2; c++)
                kf[ni][c] = *(const bf16x8*)&Kl[cur][ni * 16 + q15][c * 32 + g * 8];
        f32x4 s[4];
#pragma unroll
        for (int ni = 0; ni < 4; ni++) {
            s[ni] = mfma16(kf[ni][0], qf0, f32x4{0.f, 0.f, 0.f, 0.f});
            s[ni] = mfma16(kf[ni][1], qf1, s[ni]);
        }
        // lane holds S[k = ni*16 + g*4 + r][q = qbase + q15]; square -> P[q][k]
#pragma unroll
        for (int ni = 0; ni < 4; ni++) {
            bf16x4 p4;
#pragma unroll
            for (int r = 0; r < 4; r++) { float v = s[ni][r]; p4[r] = (bf16)(v * v); }
            *(bf16x4*)&Pw[q15][ni * 16 + g * 4] = p4;
        }
        bf16x8 pf0 = *(const bf16x8*)&Pw[q15][g * 8];
        bf16x8 pf1 = *(const bf16x8*)&Pw[q15][32 + g * 8];
        bf16x8 vf[4][2];
#pragma unroll
        for (int ni = 0; ni < 4; ni++)
#pragma unroll
            for (int c = 0; c < 2; c++)
                vf[ni][c] = *(const bf16x8*)&Vl[cur][ni * 16 + q15][c * 32 + g * 8];
#pragma unroll
        for (int ni = 0; ni < 4; ni++) {
            o[ni] = mfma16(pf0, vf[ni][0], o[ni]);
            o[ni] = mfma16(pf1, vf[ni][1], o[ni]);
        }
    };

    // ---- pipeline: 32 tiles, dbuf, one barrier per tile ----
    gloadA(0);
    stageA(0);
    gloadB(64);
    __syncthreads();                    // buf0 ready
    for (int t = 0; t <= 28; t += 2) {
        stageB(1);                      // tile t+1 -> buf1 (others read buf0)
        gloadA((t + 2) * 64);           // prefetch tile t+2
        compute(0);                     // tile t
        __syncthreads();                // buf1 ready; buf0 consumed
        stageA(0);                      // tile t+2 -> buf0
        if (t + 3 < 32) gloadB((t + 3) * 64);
        compute(1);                     // tile t+1
        __syncthreads();                // buf0 ready; buf1 consumed
    }
    // after loop: buf0 = tile 30, regs B = tile 31
    stageB(1);
    compute(0);                         // tile 30
    __syncthreads();
    compute(1);                         // tile 31

    const int b = bh / 12, h = bh % 12;
#pragma unroll
    for (int ni = 0; ni < 4; ni++)
#pragma unroll
        for (int r = 0; r < 4; r++) {
            const int s = qbase + g * 4 + r;
            AO[((long)b * S_ + s) * D_ + h * 64 + ni * 16 + q15] = (bf16)o[ni][r];
        }
}

// ---------------------------------------------------------------------------
// LayerNorm over D=768. One block per row, 256 threads (3 elems each).
// ---------------------------------------------------------------------------
template<bool WB>
__global__ __launch_bounds__(256)
void ln_kernel(const float* __restrict__ y, const float* __restrict__ gamma,
               const float* __restrict__ beta, float* __restrict__ xo,
               bf16* __restrict__ xob) {
    __shared__ float sa[4], sb[4];
    const int row = blockIdx.x, t = threadIdx.x;
    const float* yr = y + (long)row * 768;
    float v0 = yr[t], v1 = yr[t + 256], v2 = yr[t + 512];
    float s  = v0 + v1 + v2;
    float ss = v0 * v0 + v1 * v1 + v2 * v2;
#pragma unroll
    for (int o = 32; o; o >>= 1) { s += __shfl_xor(s, o); ss += __shfl_xor(ss, o); }
    if ((t & 63) == 0) { sa[t >> 6] = s; sb[t >> 6] = ss; }
    __syncthreads();
    s  = sa[0] + sa[1] + sa[2] + sa[3];
    ss = sb[0] + sb[1] + sb[2] + sb[3];
    const float mu   = s * (1.0f / 768.0f);
    const float var  = ss * (1.0f / 768.0f) - mu * mu;
    const float rstd = rsqrtf(var + 1e-5f);
    float* xr = xo + (long)row * 768;
#pragma unroll
    for (int i = 0; i < 3; i++) {
        const int c = t + i * 256;
        const float vv = (i == 0) ? v0 : (i == 1) ? v1 : v2;
        const float ov = (vv - mu) * rstd * gamma[c] + beta[c];
        xr[c] = ov;
        if (WB) xob[(long)row * 768 + c] = (bf16)ov;
    }
}

// ---------------------------------------------------------------------------
extern "C" void kernel_launch(void* const* d_in, const int* in_sizes, int n_in,
                              void* d_out, int out_size, void* d_ws, size_t ws_size,
                              hipStream_t stream) {
    const float* x     = (const float*)d_in[0];
    const float* Wq    = (const float*)d_in[1];
    const float* bq    = (const float*)d_in[2];
    const float* Wk    = (const float*)d_in[3];
    const float* bk    = (const float*)d_in[4];
    const float* Wv    = (const float*)d_in[5];
    const float* bv    = (const float*)d_in[6];
    const float* Wo    = (const float*)d_in[7];
    const float* bo    = (const float*)d_in[8];
    const float* W1    = (const float*)d_in[9];
    const float* b1    = (const float*)d_in[10];
    const float* W2    = (const float*)d_in[11];
    const float* b2    = (const float*)d_in[12];
    const float* gamma = (const float*)d_in[13];
    const float* beta  = (const float*)d_in[14];

    char* p = (char*)d_ws;
    auto alloc = [&](size_t bytes) -> void* {
        void* r = p;
        p += (bytes + 255) & ~(size_t)255;
        return r;
    };
    bf16*  Xb    = (bf16*)alloc((size_t)M_ * D_ * 2);
    bf16*  Wqkvt = (bf16*)alloc((size_t)2304 * 768 * 2);
    bf16*  Wot   = (bf16*)alloc((size_t)768 * 768 * 2);
    bf16*  W1t   = (bf16*)alloc((size_t)3072 * 768 * 2);
    bf16*  W2t   = (bf16*)alloc((size_t)768 * 3072 * 2);
    bf16*  Qh    = (bf16*)alloc((size_t)BH_ * S_ * 64 * 2);
    bf16*  Kh    = (bf16*)alloc((size_t)BH_ * S_ * 64 * 2);
    bf16*  Vt    = (bf16*)alloc((size_t)BH_ * S_ * 64 * 2);
    bf16*  AO    = (bf16*)alloc((size_t)M_ * D_ * 2);
    float* y1    = (float*)alloc((size_t)M_ * D_ * 4);
    float* x1    = (float*)alloc((size_t)M_ * D_ * 4);
    bf16*  x1b   = (bf16*)alloc((size_t)M_ * D_ * 2);
    bf16*  hbuf  = (bf16*)alloc((size_t)M_ * DFF_ * 2);
    float* y2    = y1;  // y1 dead after LN1

    // pack + transpose weights
    pack_x_kernel<<<(M_ * D_) / 1024, 256, 0, stream>>>(x, Xb);
    wt_kernel<<<dim3(12, 12), 256, 0, stream>>>(Wq, Wqkvt,              768, 768);
    wt_kernel<<<dim3(12, 12), 256, 0, stream>>>(Wk, Wqkvt + 768 * 768,  768, 768);
    wt_kernel<<<dim3(12, 12), 256, 0, stream>>>(Wv, Wqkvt + 1536 * 768, 768, 768);
    wt_kernel<<<dim3(12, 12), 256, 0, stream>>>(Wo, Wot, 768, 768);
    wt_kernel<<<dim3(48, 12), 256, 0, stream>>>(W1, W1t, 768, 3072);
    wt_kernel<<<dim3(12, 48), 256, 0, stream>>>(W2, W2t, 3072, 768);

    // QKV projection -> Qh/Kh [bh][s][dk], Vt [bh][dk][s]
    gemm_bt<0, 768, 128, 128, 2, 2><<<dim3(18, 32), 256, 0, stream>>>(
        Xb, Wqkvt, bq, bk, bv, nullptr, nullptr, nullptr, Qh, Kh, Vt);
    norm_qk_kernel<<<(2 * BH_ * S_) / 4, 256, 0, stream>>>(Qh, Kh);

    // attention
    attn_kernel<<<dim3(S_ / 64, BH_), 256, 0, stream>>>(Qh, Kh, Vt, AO);

    // out projection + residual, LN1  (64x128 tiles -> 384 blocks)
    gemm_bt<1, 768, 64, 128, 1, 4><<<dim3(6, 64), 256, 0, stream>>>(
        AO, Wot, bo, nullptr, nullptr, x, y1, nullptr, nullptr, nullptr, nullptr);
    ln_kernel<true><<<M_, 256, 0, stream>>>(y1, gamma, beta, x1, x1b);

    // FFN
    gemm_bt<2, 768, 128, 128, 2, 2><<<dim3(24, 32), 256, 0, stream>>>(
        x1b, W1t, b1, nullptr, nullptr, nullptr, nullptr, hbuf, nullptr, nullptr, nullptr);
    gemm_bt<3, 3072, 64, 128, 1, 4><<<dim3(6, 64), 256, 0, stream>>>(
        hbuf, W2t, b2, nullptr, nullptr, x1, y2, nullptr, nullptr, nullptr, nullptr);
    ln_kernel<false><<<M_, 256, 0, stream>>>(y2, gamma, beta, (float*)d_out, nullptr);
}